// Round 3
// baseline (257.368 us; speedup 1.0000x reference)
//
#include <hip/hip_runtime.h>

#define NB 128
#define NC 12
#define NL 1024
#define NDIL 7
#define NDIV 2
#define NH 32
#define NK 8
#define NKSZ 9
#define NNCP 6
#define OUTPB (NDIL*NDIV*2*NH*NK)   // 7168

__device__ __forceinline__ float4 ld4(const float* p) { return *(const float4*)p; }

__device__ __forceinline__ void argbin(const float (&a)[NK], bool valid,
                                       float (&cm)[NK], int (&cn)[NK]) {
    // grouped for v_max3/v_min3 fusion
    float mx = fmaxf(fmaxf(a[0], a[1]), a[2]);
    mx = fmaxf(fmaxf(mx, a[3]), a[4]);
    mx = fmaxf(fmaxf(mx, a[5]), a[6]);
    mx = fmaxf(mx, a[7]);
    float mn = fminf(fminf(a[0], a[1]), a[2]);
    mn = fminf(fminf(mn, a[3]), a[4]);
    mn = fminf(fminf(mn, a[5]), a[6]);
    mn = fminf(mn, a[7]);
    if (valid) {
        #pragma unroll
        for (int k = 0; k < NK; ++k) {
            cm[k] += (a[k] == mx) ? a[k] : 0.f;
            cn[k] += (a[k] == mn) ? 1 : 0;
        }
    }
}

#define ZERO4(v) { v.x = 0.f; v.y = 0.f; v.z = 0.f; v.w = 0.f; }

// generic dilation d >= 4 (d multiple of 4 -> 16B-aligned taps)
__device__ __forceinline__ void conv_generic(const float* __restrict__ gw, int d,
                                             const float (&w)[NK][NKSZ], int lane, int j,
                                             float (&cm)[NK], int (&cn)[NK]) {
    #pragma unroll
    for (int c = 0; c < 4; ++c) {
        const int pbase = 256 * c + 4 * lane;
        float4 v[NKSZ];
        #pragma unroll
        for (int t = 0; t < NKSZ; ++t) {
            const int idx = pbase + (t - 4) * d;
            if (c == 0 && t < 4) {
                const int ic = idx < 0 ? 0 : idx;
                float4 vv = ld4(gw + ic);
                if (idx < 0) ZERO4(vv);       // all-or-nothing: idx multiple of 4
                v[t] = vv;
            } else if (c == 3 && t > 4) {
                const int ic = idx > 1020 ? 1020 : idx;
                float4 vv = ld4(gw + ic);
                if (idx > 1020) ZERO4(vv);
                v[t] = vv;
            } else {
                v[t] = ld4(gw + idx);
            }
        }
        float a0[NK], a1[NK], a2[NK], a3[NK];
        #pragma unroll
        for (int k = 0; k < NK; ++k) { a0[k]=0.f; a1[k]=0.f; a2[k]=0.f; a3[k]=0.f; }
        #pragma unroll
        for (int t = 0; t < NKSZ; ++t)
            #pragma unroll
            for (int k = 0; k < NK; ++k) {
                a0[k] = fmaf(w[k][t], v[t].x, a0[k]);
                a1[k] = fmaf(w[k][t], v[t].y, a1[k]);
                a2[k] = fmaf(w[k][t], v[t].z, a2[k]);
                a3[k] = fmaf(w[k][t], v[t].w, a3[k]);
            }
        const int lastv = 1023 - j;
        argbin(a0, c < 3 || pbase     <= lastv, cm, cn);
        argbin(a1, c < 3 || pbase + 1 <= lastv, cm, cn);
        argbin(a2, c < 3 || pbase + 2 <= lastv, cm, cn);
        argbin(a3, c < 3 || pbase + 3 <= lastv, cm, cn);
    }
}

// dilation 1: sliding 12-value window, 3 b128 per 4 positions
__device__ __forceinline__ void conv_d1(const float* __restrict__ gw,
                                        const float (&w)[NK][NKSZ], int lane, int j,
                                        float (&cm)[NK], int (&cn)[NK]) {
    #pragma unroll
    for (int c = 0; c < 4; ++c) {
        const int pbase = 256 * c + 4 * lane;
        float4 r0, r1, r2;
        {
            const int i0 = pbase - 4;
            const int ic0 = (c == 0 && i0 < 0) ? 0 : i0;
            r0 = ld4(gw + ic0);
            if (c == 0 && i0 < 0) ZERO4(r0);
            r1 = ld4(gw + pbase);
            const int i2 = pbase + 4;
            const int ic2 = (c == 3 && i2 > 1020) ? 1020 : i2;
            r2 = ld4(gw + ic2);
            if (c == 3 && i2 > 1020) ZERO4(r2);
        }
        float win[12] = { r0.x, r0.y, r0.z, r0.w, r1.x, r1.y, r1.z, r1.w,
                          r2.x, r2.y, r2.z, r2.w };
        float a0[NK], a1[NK], a2[NK], a3[NK];
        #pragma unroll
        for (int k = 0; k < NK; ++k) { a0[k]=0.f; a1[k]=0.f; a2[k]=0.f; a3[k]=0.f; }
        #pragma unroll
        for (int t = 0; t < NKSZ; ++t)
            #pragma unroll
            for (int k = 0; k < NK; ++k) {
                a0[k] = fmaf(w[k][t], win[t],     a0[k]);
                a1[k] = fmaf(w[k][t], win[t + 1], a1[k]);
                a2[k] = fmaf(w[k][t], win[t + 2], a2[k]);
                a3[k] = fmaf(w[k][t], win[t + 3], a3[k]);
            }
        const int lastv = 1023 - j;
        argbin(a0, c < 3 || pbase     <= lastv, cm, cn);
        argbin(a1, c < 3 || pbase + 1 <= lastv, cm, cn);
        argbin(a2, c < 3 || pbase + 2 <= lastv, cm, cn);
        argbin(a3, c < 3 || pbase + 3 <= lastv, cm, cn);
    }
}

// dilation 2: sliding 20-value window, 5 b128 per 4 positions
__device__ __forceinline__ void conv_d2(const float* __restrict__ gw,
                                        const float (&w)[NK][NKSZ], int lane, int j,
                                        float (&cm)[NK], int (&cn)[NK]) {
    #pragma unroll
    for (int c = 0; c < 4; ++c) {
        const int pbase = 256 * c + 4 * lane;
        float win[20];
        #pragma unroll
        for (int r = 0; r < 5; ++r) {
            const int idx = pbase - 8 + 4 * r;
            float4 vv;
            if (c == 0 && r < 2) {
                const int ic = idx < 0 ? 0 : idx;
                vv = ld4(gw + ic);
                if (idx < 0) ZERO4(vv);
            } else if (c == 3 && r > 2) {
                const int ic = idx > 1020 ? 1020 : idx;
                vv = ld4(gw + ic);
                if (idx > 1020) ZERO4(vv);
            } else {
                vv = ld4(gw + idx);
            }
            win[4*r] = vv.x; win[4*r+1] = vv.y; win[4*r+2] = vv.z; win[4*r+3] = vv.w;
        }
        float a0[NK], a1[NK], a2[NK], a3[NK];
        #pragma unroll
        for (int k = 0; k < NK; ++k) { a0[k]=0.f; a1[k]=0.f; a2[k]=0.f; a3[k]=0.f; }
        #pragma unroll
        for (int t = 0; t < NKSZ; ++t)
            #pragma unroll
            for (int k = 0; k < NK; ++k) {
                a0[k] = fmaf(w[k][t], win[2*t],     a0[k]);
                a1[k] = fmaf(w[k][t], win[2*t + 1], a1[k]);
                a2[k] = fmaf(w[k][t], win[2*t + 2], a2[k]);
                a3[k] = fmaf(w[k][t], win[2*t + 3], a3[k]);
            }
        const int lastv = 1023 - j;
        argbin(a0, c < 3 || pbase     <= lastv, cm, cn);
        argbin(a1, c < 3 || pbase + 1 <= lastv, cm, cn);
        argbin(a2, c < 3 || pbase + 2 <= lastv, cm, cn);
        argbin(a3, c < 3 || pbase + 3 <= lastv, cm, cn);
    }
}

__global__ __launch_bounds__(256) void hydra_kernel(
    const float* __restrict__ X,   // [B, C, L]
    const float* __restrict__ W,   // [NDIL, NDIV, K*H, 1, KSZ]
    const int*   __restrict__ I,   // [NDIL, NDIV, H, NCP]
    float*       __restrict__ out) // [B, 28*H*K]
{
    __shared__ float g[4][NL];     // unpadded series, one per wave
    __shared__ float red[4][16];

    const int bid = blockIdx.x;
    const int h4 = bid & 7;
    const int dj = (bid >> 3) % 14;
    const int b  = (bid >> 3) / 14;
    const int di = dj >> 1;
    const int j  = dj & 1;
    const int d  = 1 << di;

    const int tid  = threadIdx.x;
    const int lane = tid & 63;
    const int wid  = __builtin_amdgcn_readfirstlane(tid >> 6);
    const int h    = h4 * 4 + wid;          // wave-uniform

    float* gw = g[wid];

    // wave-uniform channel pointers -> scalar loads
    const int* idx = I + ((di*NDIV + j)*NH + h)*NNCP;
    const float* xb = X + (size_t)b * NC * NL;
    const float* p0 = xb + idx[0]*NL;
    const float* p1 = xb + idx[1]*NL;
    const float* p2 = xb + idx[2]*NL;
    const float* p3 = xb + idx[3]*NL;
    const float* p4 = xb + idx[4]*NL;
    const float* p5 = xb + idx[5]*NL;

    if (j == 0) {
        #pragma unroll
        for (int c = 0; c < 4; ++c) {
            const int e = 256*c + 4*lane;
            float4 v0 = ld4(p0+e), v1 = ld4(p1+e), v2 = ld4(p2+e);
            float4 v3 = ld4(p3+e), v4 = ld4(p4+e), v5 = ld4(p5+e);
            float4 s;
            s.x = v0.x+v1.x+v2.x+v3.x+v4.x+v5.x;
            s.y = v0.y+v1.y+v2.y+v3.y+v4.y+v5.y;
            s.z = v0.z+v1.z+v2.z+v3.z+v4.z+v5.z;
            s.w = v0.w+v1.w+v2.w+v3.w+v4.w+v5.w;
            *(float4*)(gw + e) = s;
        }
    } else {
        // diff-of-gather == gather-of-diff (linearity): build summed series,
        // then first difference with cross-lane shuffle for the +1 neighbor.
        float4 sa[4];
        #pragma unroll
        for (int c = 0; c < 4; ++c) {
            const int e = 256*c + 4*lane;
            float4 v0 = ld4(p0+e), v1 = ld4(p1+e), v2 = ld4(p2+e);
            float4 v3 = ld4(p3+e), v4 = ld4(p4+e), v5 = ld4(p5+e);
            sa[c].x = v0.x+v1.x+v2.x+v3.x+v4.x+v5.x;
            sa[c].y = v0.y+v1.y+v2.y+v3.y+v4.y+v5.y;
            sa[c].z = v0.z+v1.z+v2.z+v3.z+v4.z+v5.z;
            sa[c].w = v0.w+v1.w+v2.w+v3.w+v4.w+v5.w;
        }
        #pragma unroll
        for (int c = 0; c < 4; ++c) {
            const float nxt_chunk = (c < 3) ? __shfl(sa[c + 1 < 4 ? c + 1 : 3].x, 0, 64) : 0.f;
            const float sh = __shfl_down(sa[c].x, 1, 64);
            const float Se4 = (lane == 63) ? nxt_chunk : sh;
            float4 df;
            df.x = sa[c].y - sa[c].x;
            df.y = sa[c].z - sa[c].y;
            df.z = sa[c].w - sa[c].z;
            df.w = Se4 - sa[c].w;
            if (c == 3 && lane == 63) df.w = 0.f;   // diff series: d[1023] = 0
            const int e = 256*c + 4*lane;
            *(float4*)(gw + e) = df;
        }
    }
    __syncthreads();

    // wave-uniform weights -> SGPRs
    const float* Wp = W + (size_t)((di*NDIV + j)*(NK*NH) + h*NK) * NKSZ;
    float w[NK][NKSZ];
    #pragma unroll
    for (int k = 0; k < NK; ++k)
        #pragma unroll
        for (int t = 0; t < NKSZ; ++t)
            w[k][t] = Wp[k*NKSZ + t];

    float cm[NK];
    int   cn[NK];
    #pragma unroll
    for (int k = 0; k < NK; ++k) { cm[k] = 0.f; cn[k] = 0; }

    if (di == 0)      conv_d1(gw, w, lane, j, cm, cn);
    else if (di == 1) conv_d2(gw, w, lane, j, cm, cn);
    else              conv_generic(gw, d, w, lane, j, cm, cn);

    // wave reduction: 16 bins, amortized over 1024 positions
    #pragma unroll
    for (int k = 0; k < NK; ++k) {
        #pragma unroll
        for (int s = 32; s > 0; s >>= 1) {
            cm[k] += __shfl_down(cm[k], s, 64);
            cn[k] += __shfl_down(cn[k], s, 64);
        }
    }
    if (lane == 0) {
        #pragma unroll
        for (int k = 0; k < NK; ++k) {
            red[wid][k]     = cm[k];
            red[wid][8 + k] = (float)cn[k];
        }
    }
    __syncthreads();

    if (tid < 64) {
        const int ws = tid >> 4, slot = tid & 15;
        const int mm = slot >> 3, k = slot & 7;
        const int ho = h4*4 + ws;
        const int z  = dj*2 + mm;                 // [max, min] per (di,j)
        out[(size_t)b*OUTPB + z*(NH*NK) + ho*NK + k] = red[ws][slot];
    }
}

extern "C" void kernel_launch(void* const* d_in, const int* in_sizes, int n_in,
                              void* d_out, int out_size, void* d_ws, size_t ws_size,
                              hipStream_t stream) {
    const float* X = (const float*)d_in[0];
    const float* W = (const float*)d_in[1];
    const int*   I = (const int*)d_in[2];
    float* out = (float*)d_out;

    const int nblocks = NB * (NDIL*NDIV) * (NH/4);   // 14336
    hydra_kernel<<<dim3(nblocks), dim3(256), 0, stream>>>(X, W, I, out);
}